// Round 4
// baseline (192.795 us; speedup 1.0000x reference)
//
#include <hip/hip_runtime.h>
#include <stdint.h>

#define N      6144
#define F      128
#define D      32
#define H      4
#define HID    128
#define NP1    6145
#define CHK    128
#define NCHK   48      // chunks per head
#define SEGL   96      // rows per scan segment
#define NSEG   64      // segments per head
#define NBLK   768
#define NTHR   256

// ---- device scratch ----
__device__ float    g_Wh[(size_t)N * HID];
__device__ float    g_es[H * N];
__device__ float    g_ed[H * N];
__device__ uint64_t g_keys[H * N];
__device__ float    g_dsv[H * N];
__device__ int      g_perm[H * N];
__device__ float    g_SEG[H * 66 * NSEG];
__device__ float    g_VEC[(size_t)H * NP1 * 64];  // [h][k][c] c<32: u*wh pfx, c>=32: v*wh pfx
__device__ float    g_SCL[(size_t)H * NP1 * 2];   // [h][k][{u1,v1}]
__device__ float    g_PART[H * 96 * 32];

// ---- dataflow counters (separate cachelines; reset by last eval block) ----
__device__ unsigned g_cnt[8 * 32];
#define SL1 0
#define SL2 1
#define SL3 2
#define SL4A 3
#define SL4 4
#define SL5 5

__device__ __forceinline__ void publish(int slot) {
    __syncthreads();
    if (threadIdx.x == 0)
        __hip_atomic_fetch_add(&g_cnt[slot * 32], 1u,
                               __ATOMIC_RELEASE, __HIP_MEMORY_SCOPE_AGENT);
}
__device__ __forceinline__ void waitfor(int slot, unsigned target) {
    if (threadIdx.x == 0) {
        unsigned it = 0;
        while (__hip_atomic_load(&g_cnt[slot * 32], __ATOMIC_RELAXED,
                                 __HIP_MEMORY_SCOPE_AGENT) < target) {
            __builtin_amdgcn_s_sleep(4);
            if (++it > (1u << 22)) break;   // safety valve (never hit if protocol correct)
        }
        (void)__hip_atomic_load(&g_cnt[slot * 32], __ATOMIC_ACQUIRE,
                                __HIP_MEMORY_SCOPE_AGENT);
    }
    __syncthreads();
}

__device__ __forceinline__ uint32_t f2mono(float f) {
    uint32_t u = __float_as_uint(f);
    return (u & 0x80000000u) ? ~u : (u | 0x80000000u);
}

union SmemU {
    struct { uint64_t k[CHK]; int part[CHK][2]; } p2;
    struct { uint64_t ks[N]; } p3;                                   // 48 KB
    struct { float whL[SEGL * 33]; float e1[SEGL]; float e2[SEGL];
             int permL[SEGL]; float tile[SEGL * 69]; float offArr[68]; } p4;
    struct { float ds[N]; float hm[HID]; } p5;
};

__global__ __launch_bounds__(NTHR) void mega2(
        const float* __restrict__ x, const float* __restrict__ W,
        const float* __restrict__ a_src, const float* __restrict__ a_dst,
        const float* __restrict__ W_fc, const float* __restrict__ b_fc,
        float* __restrict__ out)
{
    __shared__ SmemU sm;
    __shared__ int sm_last;
    const int tid = threadIdx.x;
    const int bid = blockIdx.x;
    const int lane = tid & 63;
    const int wv = tid >> 6;

    // ============ Duty 1 (all 768 blocks): Wh = x@W, e_s/e_d ============
    {
        int rg = wv & 1;            // row group
        int ch = wv >> 1;           // column half
        int row0 = __builtin_amdgcn_readfirstlane(bid * 8 + rg * 4);
        int col = ch * 64 + lane;   // 0..127
        int h = col >> 5;
        const float* __restrict__ xr = x + (size_t)row0 * F;
        const float* __restrict__ Wp = W + h * (F * D) + (col & 31);
        float acc[4] = {0.f, 0.f, 0.f, 0.f};
#pragma unroll 4
        for (int f = 0; f < F; ++f) {
            float w = Wp[f * D];
            acc[0] = fmaf(xr[f], w, acc[0]);
            acc[1] = fmaf(xr[F + f], w, acc[1]);
            acc[2] = fmaf(xr[2 * F + f], w, acc[2]);
            acc[3] = fmaf(xr[3 * F + f], w, acc[3]);
        }
        float as = a_src[col], ad = a_dst[col];
#pragma unroll
        for (int r = 0; r < 4; ++r) {
            int n = row0 + r;
            g_Wh[(size_t)n * HID + col] = acc[r];
            float ts = acc[r] * as, td = acc[r] * ad;
#pragma unroll
            for (int m = 1; m < 32; m <<= 1) {
                ts += __shfl_xor(ts, m);
                td += __shfl_xor(td, m);
            }
            if ((lane & 31) == 0) { g_es[h * N + n] = ts; g_ed[h * N + n] = td; }
        }
        publish(SL1);
    }

    // ============ Duty 2 (blocks 0..191): sort 128-key chunks ============
    if (bid < H * NCHK) {
        waitfor(SL1, NBLK);
        int h = bid / NCHK, c = bid % NCHK;
        if (tid < CHK) {
            int j = c * CHK + tid;
            sm.p2.k[tid] = (((uint64_t)f2mono(g_ed[h * N + j])) << 13) | (uint32_t)j;
        }
        __syncthreads();
        {
            int it = tid & 127, q = tid >> 7;
            uint64_t myk = sm.p2.k[it];
            int cnt = 0;
            for (int s2 = q * 64; s2 < q * 64 + 64; ++s2)
                cnt += (sm.p2.k[s2] < myk) ? 1 : 0;
            sm.p2.part[it][q] = cnt;
        }
        __syncthreads();
        if (tid < CHK) {
            int rank = sm.p2.part[tid][0] + sm.p2.part[tid][1];
            g_keys[h * N + c * CHK + rank] = sm.p2.k[tid];
        }
        publish(SL2);
    }

    // ============ Duty 3 (blocks 0..95): global rank -> dsv, perm ============
    if (bid < 96) {
        waitfor(SL2, H * NCHK);
        int h = bid / 24;
        int sbase = (bid % 24) * 256;
        const uint64_t* kh = g_keys + (size_t)h * N;
        for (int r = tid; r < N; r += NTHR) sm.p3.ks[r] = kh[r];
        __syncthreads();
        int slot = sbase + tid;
        uint64_t myk = sm.p3.ks[slot];
        int rank = slot & (CHK - 1);
        int cown = slot >> 7;
        for (int cc = 0; cc < NCHK; ++cc) {
            if (cc == cown) continue;
            int base = cc * CHK;
            int pos = 0;
#pragma unroll
            for (int st = CHK; st >= 1; st >>= 1) {
                int np = pos + st;
                if (np <= CHK && sm.p3.ks[base + np - 1] < myk) pos = np;
            }
            rank += pos;
        }
        uint32_t m = (uint32_t)(myk >> 13);
        uint32_t u = (m & 0x80000000u) ? (m ^ 0x80000000u) : ~m;
        g_dsv[h * N + rank] = __uint_as_float(u);
        g_perm[h * N + rank] = (int)(myk & 8191u);
        publish(SL3);
    }

    // ============ Duty 4 (blocks 0..255): segment scans ============
    if (bid < H * NSEG) {
        waitfor(SL3, 96);
        int h = bid >> 6, seg = bid & 63;
        int r0 = seg * SEGL;
        if (tid < SEGL) {
            sm.p4.permL[tid] = g_perm[h * N + r0 + tid];
            float dv = g_dsv[h * N + r0 + tid];
            sm.p4.e1[tid] = expf(0.01f * dv);
            sm.p4.e2[tid] = expf(dv);
        }
        __syncthreads();
        if (tid < 192) {            // gather Wh rows -> whL[96][33]
            int row = tid >> 1, half = tid & 1;
            int j = sm.p4.permL[row];
            const float4* src = (const float4*)&g_Wh[(size_t)j * HID + h * D + half * 16];
            float4 A = src[0], B = src[1], C = src[2], E = src[3];
            float* w = &sm.p4.whL[row * 33 + half * 16];
            w[0]=A.x; w[1]=A.y; w[2]=A.z; w[3]=A.w;
            w[4]=B.x; w[5]=B.y; w[6]=B.z; w[7]=B.w;
            w[8]=C.x; w[9]=C.y; w[10]=C.z; w[11]=C.w;
            w[12]=E.x; w[13]=E.y; w[14]=E.z; w[15]=E.w;
        }
        __syncthreads();
        // 66 component scans (4 waves, c = wv + 4k)
        for (int k = 0; k < 17; ++k) {
            int c = wv + 4 * k;
            if (c >= 66) break;
            float p_lo, p_hi;
            if (c < 64) {
                int fam = c >> 5, d = c & 31;
                const float* e = fam ? sm.p4.e2 : sm.p4.e1;
                p_lo = e[lane] * sm.p4.whL[lane * 33 + d];
                p_hi = (lane < 32) ? e[64 + lane] * sm.p4.whL[(64 + lane) * 33 + d] : 0.f;
            } else {
                const float* e = (c == 65) ? sm.p4.e2 : sm.p4.e1;
                p_lo = e[lane];
                p_hi = (lane < 32) ? e[64 + lane] : 0.f;
            }
            float s_lo = p_lo;
#pragma unroll
            for (int m = 1; m < 64; m <<= 1) {
                float t = __shfl_up(s_lo, m);
                if (lane >= m) s_lo += t;
            }
            float tot_lo = __shfl(s_lo, 63);
            float s_hi = p_hi;
#pragma unroll
            for (int m = 1; m < 32; m <<= 1) {
                float t = __shfl_up(s_hi, m);
                if (lane >= m) s_hi += t;
            }
            float tot_hi = __shfl(s_hi, 31);
            sm.p4.tile[lane * 69 + c] = s_lo;
            if (lane < 32) sm.p4.tile[(64 + lane) * 69 + c] = tot_lo + s_hi;
            if (lane == 0) g_SEG[(h * 66 + c) * NSEG + seg] = tot_lo + tot_hi;
        }
        publish(SL4A);
        waitfor(SL4A, H * NSEG);
        for (int k = 0; k < 17; ++k) {
            int c = wv + 4 * k;
            if (c >= 66) break;
            float sv = g_SEG[(h * 66 + c) * NSEG + lane];
            float msk = (lane < seg) ? sv : 0.f;
#pragma unroll
            for (int m = 1; m < 64; m <<= 1) msk += __shfl_xor(msk, m);
            if (lane == 0) sm.p4.offArr[c] = msk;
        }
        __syncthreads();
        float* vec = g_VEC + (size_t)h * NP1 * 64;
        for (int t = tid; t < SEGL * 64; t += NTHR) {
            int row = t >> 6, c = t & 63;
            vec[(size_t)(r0 + row + 1) * 64 + c] = sm.p4.tile[row * 69 + c] + sm.p4.offArr[c];
        }
        float* scl = g_SCL + (size_t)h * NP1 * 2;
        for (int t = tid; t < SEGL * 2; t += NTHR) {
            int row = t >> 1, c = t & 1;
            scl[(size_t)(r0 + row + 1) * 2 + c] = sm.p4.tile[row * 69 + 64 + c] + sm.p4.offArr[64 + c];
        }
        if (seg == 0) {
            if (tid < 64) vec[tid] = 0.f;
            else if (tid < 66) scl[tid - 64] = 0.f;
        }
        publish(SL4);
    }

    // ============ Duty 5 (blocks 0..383): eval + finalize ============
    if (bid < H * 96) {
        waitfor(SL4, H * NSEG);
        int h = bid / 96;
        int ibase = (bid % 96) * 64;
        for (int r = tid; r < N; r += NTHR) sm.p5.ds[r] = g_dsv[h * N + r];
        __syncthreads();
        const float* vec = g_VEC + (size_t)h * NP1 * 64;
        const float* scl = g_SCL + (size_t)h * NP1 * 2;
        int q = wv;                     // quarter: d-range q*8..q*8+7
        float vt[8];
#pragma unroll
        for (int j = 0; j < 8; ++j) vt[j] = vec[(size_t)N * 64 + 32 + q * 8 + j];
        float v1T = scl[(size_t)N * 2 + 1];

        int i = ibase + lane;
        float s = g_es[h * N + i];
        float nst = -s;
        int k = 0;
#pragma unroll
        for (int st = 4096; st >= 1; st >>= 1) {
            int np = k + st;
            if (np <= N && sm.p5.ds[np - 1] <= nst) k = np;
        }
        float e1 = expf(0.01f * s), e2 = expf(s);
        float pu1 = scl[(size_t)k * 2 + 0];
        float pv1 = scl[(size_t)k * 2 + 1];
        float inv = 1.0f / (e1 * pu1 + e2 * (v1T - pv1));
        const float4* U = (const float4*)&vec[(size_t)k * 64 + q * 8];
        const float4* V = (const float4*)&vec[(size_t)k * 64 + 32 + q * 8];
        float4 u0 = U[0], u1 = U[1], v0 = V[0], v1 = V[1];
        float uu[8] = {u0.x,u0.y,u0.z,u0.w,u1.x,u1.y,u1.z,u1.w};
        float vv[8] = {v0.x,v0.y,v0.z,v0.w,v1.x,v1.y,v1.z,v1.w};
        float acc[8];
#pragma unroll
        for (int j = 0; j < 8; ++j) {
            float num = e1 * uu[j] + e2 * (vt[j] - vv[j]);
            acc[j] = fmaxf(num, 0.f) * inv;     // relu(elu(x)) == relu(x); denom > 0
        }
#pragma unroll
        for (int j = 0; j < 8; ++j) {
#pragma unroll
            for (int m = 1; m < 64; m <<= 1) acc[j] += __shfl_xor(acc[j], m);
        }
        if (lane == 0) {
#pragma unroll
            for (int j = 0; j < 8; ++j)
                g_PART[bid * 32 + q * 8 + j] = acc[j];
        }
        __syncthreads();
        if (tid == 0) {
            unsigned r5 = __hip_atomic_fetch_add(&g_cnt[SL5 * 32], 1u,
                              __ATOMIC_ACQ_REL, __HIP_MEMORY_SCOPE_AGENT);
            sm_last = (r5 == (unsigned)(H * 96 - 1));
        }
        __syncthreads();
        if (sm_last) {
            // one unique block finalizes: mean + fc2 + counter reset
            if (tid < HID) {
                int hh = tid >> 5, dd = tid & 31;
                float sum = 0.f;
                for (int s2 = 0; s2 < 96; ++s2)
                    sum += g_PART[(hh * 96 + s2) * 32 + dd];
                sm.p5.hm[tid] = sum * (1.0f / (float)N);
            }
            __syncthreads();
            if (tid < 128) {
                float y = b_fc[tid];
#pragma unroll 8
                for (int c = 0; c < 128; ++c)
                    y = fmaf(sm.p5.hm[c], W_fc[c * 128 + tid], y);
                out[tid] = y;
            }
            __syncthreads();
            if (tid < 8)
                __hip_atomic_store(&g_cnt[tid * 32], 0u,
                                   __ATOMIC_RELEASE, __HIP_MEMORY_SCOPE_AGENT);
        }
    }
}

extern "C" void kernel_launch(void* const* d_in, const int* in_sizes, int n_in,
                              void* d_out, int out_size, void* d_ws, size_t ws_size,
                              hipStream_t stream) {
    (void)in_sizes; (void)n_in; (void)d_ws; (void)ws_size; (void)out_size;
    const float* x     = (const float*)d_in[0];
    const float* W     = (const float*)d_in[1];
    const float* a_src = (const float*)d_in[2];
    const float* a_dst = (const float*)d_in[3];
    const float* W_fc  = (const float*)d_in[4];
    const float* b_fc  = (const float*)d_in[5];
    float* out = (float*)d_out;

    mega2<<<dim3(NBLK), dim3(NTHR), 0, stream>>>(x, W, a_src, a_dst, W_fc, b_fc, out);
}

// Round 5
// 143.674 us; speedup vs baseline: 1.3419x; 1.3419x over previous
//
#include <hip/hip_runtime.h>
#include <stdint.h>

#define N      6144
#define F      128
#define D      32
#define H      4
#define HID    128
#define NP1    6145
#define CHK    256
#define NCHK   24      // chunks per head
#define SEGL   96      // rows per scan segment
#define NSEG   64      // segments per head
#define NBLK   768
#define NTHR   256
#define NSHARD 32

// ---- device scratch ----
__device__ float    g_Wh[(size_t)N * HID];
__device__ float    g_es[H * N];
__device__ float    g_ed[H * N];
__device__ uint64_t g_keys[H * N];
__device__ float    g_dsv[H * N];
__device__ int      g_perm[H * N];
__device__ float    g_SEG[H * 66 * NSEG];
__device__ float    g_VEC[(size_t)H * NP1 * 64];  // [h][k][c] c<32: u*wh pfx, c>=32: v*wh pfx
__device__ float    g_SCL[(size_t)H * NP1 * 2];   // [h][k][{u1,v1}]
__device__ float    g_PART[H * 96 * 32];

// ---- sharded dataflow counters: [slot][shard][pad to 128B line] ----
__device__ unsigned g_cnt[6][NSHARD][32];
#define SL1  0
#define SL2  1
#define SL3  2
#define SL4A 3
#define SL4  4
#define SL5  5

__device__ __forceinline__ void publish(int slot) {
    __syncthreads();
    if (threadIdx.x == 0)
        __hip_atomic_fetch_add(&g_cnt[slot][blockIdx.x & (NSHARD - 1)][0], 1u,
                               __ATOMIC_RELEASE, __HIP_MEMORY_SCOPE_AGENT);
}

__device__ __forceinline__ void waitfor(int slot, unsigned target) {
    if (threadIdx.x < 64) {
        int lane = threadIdx.x;
        unsigned it = 0;
        for (;;) {
            unsigned c = 0;
            if (lane < NSHARD)
                c = __hip_atomic_load(&g_cnt[slot][lane][0],
                                      __ATOMIC_RELAXED, __HIP_MEMORY_SCOPE_AGENT);
            unsigned s = c;
#pragma unroll
            for (int m = 1; m < 64; m <<= 1) s += __shfl_xor(s, m);
            if (s >= target) break;
            __builtin_amdgcn_s_sleep(2);
            if (++it > (1u << 20)) break;   // safety valve
        }
        __builtin_amdgcn_fence(__ATOMIC_ACQUIRE, "agent");
    }
    __syncthreads();
}

__device__ __forceinline__ uint32_t f2mono(float f) {
    uint32_t u = __float_as_uint(f);
    return (u & 0x80000000u) ? ~u : (u | 0x80000000u);
}

union SmemU {
    struct { uint64_t k[CHK]; } p2;
    struct { uint64_t ks[N]; int part[32][8]; } p3;                  // 50176 B
    struct { float whL[SEGL * 33]; float e1[SEGL]; float e2[SEGL];
             int permL[SEGL]; float tile[SEGL * 69]; float offArr[68]; } p4;
    struct { float ds[N]; float hm[HID]; } p5;
};

__global__ __launch_bounds__(NTHR) void mega3(
        const float* __restrict__ x, const float* __restrict__ W,
        const float* __restrict__ a_src, const float* __restrict__ a_dst,
        const float* __restrict__ W_fc, const float* __restrict__ b_fc,
        float* __restrict__ out)
{
    __shared__ SmemU sm;
    const int tid = threadIdx.x;
    const int bid = blockIdx.x;
    const int lane = tid & 63;
    const int wv = tid >> 6;

    // ============ Duty 1 (all 768): Wh = x@W, e_s/e_d ============
    {
        int rg = wv & 1;
        int ch = wv >> 1;
        int row0 = __builtin_amdgcn_readfirstlane(bid * 8 + rg * 4);
        int col = ch * 64 + lane;   // 0..127
        int h = col >> 5;
        const float* __restrict__ xr = x + (size_t)row0 * F;
        const float* __restrict__ Wp = W + h * (F * D) + (col & 31);
        float acc[4] = {0.f, 0.f, 0.f, 0.f};
#pragma unroll 4
        for (int f = 0; f < F; ++f) {
            float w = Wp[f * D];
            acc[0] = fmaf(xr[f], w, acc[0]);
            acc[1] = fmaf(xr[F + f], w, acc[1]);
            acc[2] = fmaf(xr[2 * F + f], w, acc[2]);
            acc[3] = fmaf(xr[3 * F + f], w, acc[3]);
        }
        float as = a_src[col], ad = a_dst[col];
#pragma unroll
        for (int r = 0; r < 4; ++r) {
            int n = row0 + r;
            g_Wh[(size_t)n * HID + col] = acc[r];
            float ts = acc[r] * as, td = acc[r] * ad;
#pragma unroll
            for (int m = 1; m < 32; m <<= 1) {
                ts += __shfl_xor(ts, m);
                td += __shfl_xor(td, m);
            }
            if ((lane & 31) == 0) { g_es[h * N + n] = ts; g_ed[h * N + n] = td; }
        }
        publish(SL1);
    }

    // ============ Duty 2 (96 blocks): sort 256-key chunks ============
    if (bid < H * NCHK) {
        waitfor(SL1, NBLK);
        int h = bid / NCHK, c = bid % NCHK;
        int j = c * CHK + tid;
        uint64_t myk = (((uint64_t)f2mono(g_ed[h * N + j])) << 13) | (uint32_t)j;
        sm.p2.k[tid] = myk;
        __syncthreads();
        int rank = 0;
        for (int s2 = 0; s2 < CHK; ++s2)
            rank += (sm.p2.k[s2] < myk) ? 1 : 0;
        g_keys[h * N + c * CHK + rank] = myk;
        publish(SL2);
    }

    // ============ Duty 3 (all 768): global rank -> dsv, perm ============
    {
        waitfor(SL2, H * NCHK);
        int h = bid / 192;
        int ibase = (bid % 192) * 32;
        const uint64_t* kh = g_keys + (size_t)h * N;
        for (int r = tid; r < N; r += NTHR) sm.p3.ks[r] = kh[r];
        __syncthreads();
        {
            int item = tid & 31, sl = tid >> 5;    // 8 slices x 3 chunks
            int slot = ibase + item;
            uint64_t myk = sm.p3.ks[slot];
            int cown = slot >> 8;
            int cnt = 0;
            for (int cc = sl * 3; cc < sl * 3 + 3; ++cc) {
                if (cc == cown) continue;
                int base = cc * CHK;
                int pos = 0;
#pragma unroll
                for (int st = CHK; st >= 1; st >>= 1) {
                    int np = pos + st;
                    if (np <= CHK && sm.p3.ks[base + np - 1] < myk) pos = np;
                }
                cnt += pos;
            }
            sm.p3.part[item][sl] = cnt;
        }
        __syncthreads();
        if (tid < 32) {
            int slot = ibase + tid;
            uint64_t myk = sm.p3.ks[slot];
            int rank = slot & (CHK - 1);
#pragma unroll
            for (int sl = 0; sl < 8; ++sl) rank += sm.p3.part[tid][sl];
            uint32_t m = (uint32_t)(myk >> 13);
            uint32_t u = (m & 0x80000000u) ? (m ^ 0x80000000u) : ~m;
            g_dsv[h * N + rank] = __uint_as_float(u);
            g_perm[h * N + rank] = (int)(myk & 8191u);
        }
        publish(SL3);
    }

    // ============ Duty 4 (256 blocks): segment scans ============
    if (bid < H * NSEG) {
        waitfor(SL3, NBLK);
        int h = bid >> 6, seg = bid & 63;
        int r0 = seg * SEGL;
        if (tid < SEGL) {
            sm.p4.permL[tid] = g_perm[h * N + r0 + tid];
            float dv = g_dsv[h * N + r0 + tid];
            sm.p4.e1[tid] = expf(0.01f * dv);
            sm.p4.e2[tid] = expf(dv);
        }
        __syncthreads();
        if (tid < 192) {            // gather Wh rows -> whL[96][33]
            int row = tid >> 1, half = tid & 1;
            int j = sm.p4.permL[row];
            const float4* src = (const float4*)&g_Wh[(size_t)j * HID + h * D + half * 16];
            float4 A = src[0], B = src[1], C = src[2], E = src[3];
            float* w = &sm.p4.whL[row * 33 + half * 16];
            w[0]=A.x; w[1]=A.y; w[2]=A.z; w[3]=A.w;
            w[4]=B.x; w[5]=B.y; w[6]=B.z; w[7]=B.w;
            w[8]=C.x; w[9]=C.y; w[10]=C.z; w[11]=C.w;
            w[12]=E.x; w[13]=E.y; w[14]=E.z; w[15]=E.w;
        }
        __syncthreads();
        for (int k = 0; k < 17; ++k) {
            int c = wv + 4 * k;
            if (c >= 66) break;
            float p_lo, p_hi;
            if (c < 64) {
                int fam = c >> 5, d = c & 31;
                const float* e = fam ? sm.p4.e2 : sm.p4.e1;
                p_lo = e[lane] * sm.p4.whL[lane * 33 + d];
                p_hi = (lane < 32) ? e[64 + lane] * sm.p4.whL[(64 + lane) * 33 + d] : 0.f;
            } else {
                const float* e = (c == 65) ? sm.p4.e2 : sm.p4.e1;
                p_lo = e[lane];
                p_hi = (lane < 32) ? e[64 + lane] : 0.f;
            }
            float s_lo = p_lo;
#pragma unroll
            for (int m = 1; m < 64; m <<= 1) {
                float t = __shfl_up(s_lo, m);
                if (lane >= m) s_lo += t;
            }
            float tot_lo = __shfl(s_lo, 63);
            float s_hi = p_hi;
#pragma unroll
            for (int m = 1; m < 32; m <<= 1) {
                float t = __shfl_up(s_hi, m);
                if (lane >= m) s_hi += t;
            }
            float tot_hi = __shfl(s_hi, 31);
            sm.p4.tile[lane * 69 + c] = s_lo;
            if (lane < 32) sm.p4.tile[(64 + lane) * 69 + c] = tot_lo + s_hi;
            if (lane == 0) g_SEG[(h * 66 + c) * NSEG + seg] = tot_lo + tot_hi;
        }
        publish(SL4A);
        waitfor(SL4A, H * NSEG);
        for (int k = 0; k < 17; ++k) {
            int c = wv + 4 * k;
            if (c >= 66) break;
            float sv = g_SEG[(h * 66 + c) * NSEG + lane];
            float msk = (lane < seg) ? sv : 0.f;
#pragma unroll
            for (int m = 1; m < 64; m <<= 1) msk += __shfl_xor(msk, m);
            if (lane == 0) sm.p4.offArr[c] = msk;
        }
        __syncthreads();
        float* vec = g_VEC + (size_t)h * NP1 * 64;
        for (int t = tid; t < SEGL * 64; t += NTHR) {
            int row = t >> 6, c = t & 63;
            vec[(size_t)(r0 + row + 1) * 64 + c] = sm.p4.tile[row * 69 + c] + sm.p4.offArr[c];
        }
        float* scl = g_SCL + (size_t)h * NP1 * 2;
        for (int t = tid; t < SEGL * 2; t += NTHR) {
            int row = t >> 1, c = t & 1;
            scl[(size_t)(r0 + row + 1) * 2 + c] = sm.p4.tile[row * 69 + 64 + c] + sm.p4.offArr[64 + c];
        }
        if (seg == 0) {
            if (tid < 64) vec[tid] = 0.f;
            else if (tid < 66) scl[tid - 64] = 0.f;
        }
        publish(SL4);
    }

    // ============ Duty 5 (384 blocks): eval ============
    if (bid < H * 96) {
        waitfor(SL4, H * NSEG);
        int h = bid / 96;
        int ibase = (bid % 96) * 64;
        for (int r = tid; r < N; r += NTHR) sm.p5.ds[r] = g_dsv[h * N + r];
        __syncthreads();
        const float* vec = g_VEC + (size_t)h * NP1 * 64;
        const float* scl = g_SCL + (size_t)h * NP1 * 2;
        int q = wv;
        float vt[8];
#pragma unroll
        for (int j = 0; j < 8; ++j) vt[j] = vec[(size_t)N * 64 + 32 + q * 8 + j];
        float v1T = scl[(size_t)N * 2 + 1];

        int i = ibase + lane;
        float s = g_es[h * N + i];
        float nst = -s;
        int k = 0;
#pragma unroll
        for (int st = 4096; st >= 1; st >>= 1) {
            int np = k + st;
            if (np <= N && sm.p5.ds[np - 1] <= nst) k = np;
        }
        float e1 = expf(0.01f * s), e2 = expf(s);
        float pu1 = scl[(size_t)k * 2 + 0];
        float pv1 = scl[(size_t)k * 2 + 1];
        float inv = 1.0f / (e1 * pu1 + e2 * (v1T - pv1));
        const float4* U = (const float4*)&vec[(size_t)k * 64 + q * 8];
        const float4* V = (const float4*)&vec[(size_t)k * 64 + 32 + q * 8];
        float4 u0 = U[0], u1 = U[1], v0 = V[0], v1 = V[1];
        float uu[8] = {u0.x,u0.y,u0.z,u0.w,u1.x,u1.y,u1.z,u1.w};
        float vv[8] = {v0.x,v0.y,v0.z,v0.w,v1.x,v1.y,v1.z,v1.w};
        float acc[8];
#pragma unroll
        for (int j = 0; j < 8; ++j) {
            float num = e1 * uu[j] + e2 * (vt[j] - vv[j]);
            acc[j] = fmaxf(num, 0.f) * inv;     // relu(elu(x)) == relu(x); denom > 0
        }
#pragma unroll
        for (int j = 0; j < 8; ++j) {
#pragma unroll
            for (int m = 1; m < 64; m <<= 1) acc[j] += __shfl_xor(acc[j], m);
        }
        if (lane == 0) {
#pragma unroll
            for (int j = 0; j < 8; ++j)
                g_PART[bid * 32 + q * 8 + j] = acc[j];
        }
        publish(SL5);
    }

    // ============ Finalize (block 0 only, deterministic) ============
    if (bid == 0) {
        waitfor(SL5, H * 96);
        if (tid < HID) {
            int hh = tid >> 5, dd = tid & 31;
            float sum = 0.f;
            for (int s2 = 0; s2 < 96; ++s2)
                sum += g_PART[(hh * 96 + s2) * 32 + dd];
            sm.p5.hm[tid] = sum * (1.0f / (float)N);
        }
        __syncthreads();
        if (tid < 128) {
            float y = b_fc[tid];
#pragma unroll 8
            for (int c = 0; c < 128; ++c)
                y = fmaf(sm.p5.hm[c], W_fc[c * 128 + tid], y);
            out[tid] = y;
        }
        __syncthreads();
        // reset all counters for next graph replay (no one polls anymore)
        if (tid < 6 * NSHARD)
            __hip_atomic_store(&g_cnt[tid / NSHARD][tid % NSHARD][0], 0u,
                               __ATOMIC_RELEASE, __HIP_MEMORY_SCOPE_AGENT);
    }
}

extern "C" void kernel_launch(void* const* d_in, const int* in_sizes, int n_in,
                              void* d_out, int out_size, void* d_ws, size_t ws_size,
                              hipStream_t stream) {
    (void)in_sizes; (void)n_in; (void)d_ws; (void)ws_size; (void)out_size;
    const float* x     = (const float*)d_in[0];
    const float* W     = (const float*)d_in[1];
    const float* a_src = (const float*)d_in[2];
    const float* a_dst = (const float*)d_in[3];
    const float* W_fc  = (const float*)d_in[4];
    const float* b_fc  = (const float*)d_in[5];
    float* out = (float*)d_out;

    mega3<<<dim3(NBLK), dim3(NTHR), 0, stream>>>(x, W, a_src, a_dst, W_fc, b_fc, out);
}